// Round 9
// baseline (291.944 us; speedup 1.0000x reference)
//
#include <hip/hip_runtime.h>
#include <cstdint>

#define BSZ 512
#define NG 5
#define NEL 32
#define IN_C 5
#define HC 64
#define NN (BSZ * NG * NEL)   // 81920 nodes
#define NE (NN * 16)          // 1310720 edges
#define NC 3
#define KTOT (NG * NEL * HC)  // 10240
#define NSLICE 32             // K split one electrode per slice (was 16)
#define NCB 320               // coarse buckets (256 nodes each, dst>>8)
#define CCHUNK 2048           // edges per partition block (640 blocks; measured optimum)
#define NBLK1 (NE / CCHUNK)   // 640
#define SORTCAP 5120          // fixed bucket slab capacity (avg 4096, +16 sigma)
#define INITB (NN * 64 / 256) // 20480 init blocks fused into part1

typedef __attribute__((ext_vector_type(8))) short bf16x8;
typedef __attribute__((ext_vector_type(4))) float f32x4;

__device__ __forceinline__ float bcast(float v, int l) {
  return __int_as_float(__builtin_amdgcn_readlane(__float_as_int(v), l));
}

__device__ __forceinline__ ushort bf16r(float f) {   // RNE f32->bf16
  unsigned u = __float_as_uint(f);
  return (ushort)((u + 0x7FFFu + ((u >> 16) & 1u)) >> 16);
}

__device__ __forceinline__ float bf16f(ushort s) {
  return __uint_as_float(((unsigned)s) << 16);
}

__device__ __forceinline__ float sigmoidf_(float x) {
  return 1.0f / (1.0f + __expf(-x));
}

__device__ __forceinline__ float tanhf_(float x) {
  x = fminf(fmaxf(x, -15.0f), 15.0f);
  float e = __expf(2.0f * x);
  return (e - 1.0f) / (e + 1.0f);
}

// ---------------- fused partition + init ----------------
// Blocks [0,NBLK1): one-phase partition into fixed-capacity bucket slabs
//   (CCHUNK=2048: measured optimum).
// Blocks [NBLK1, ...): init — hb, layer-0 m16 (5 nonzero K-cols collapse the
//   GEMM to 5 FMAs), W1->bf16, GRU/Wg1 weights -> fragment layout.
__global__ void __launch_bounds__(256) k_part1(
    const int* __restrict__ ei, const float* __restrict__ ea,
    int* __restrict__ gcnt, int* __restrict__ ent4,
    unsigned char* __restrict__ dstlo,
    const float* __restrict__ x, const float* __restrict__ Wg0,
    ushort* __restrict__ hb, ushort* __restrict__ m16,
    const float* __restrict__ W1, ushort* __restrict__ w1b,
    const float* __restrict__ wih, const float* __restrict__ whh,
    const float* __restrict__ wgn,
    ushort* __restrict__ wihb, ushort* __restrict__ whhb,
    ushort* __restrict__ wgnb) {
  __shared__ int lent[CCHUNK];   // 8 KB
  __shared__ int lkey[CCHUNK];   // 8 KB
  __shared__ int lhist[NCB];
  __shared__ int lcur[NCB];
  __shared__ int delta[NCB];
  __shared__ int sc[256];
  const int t = threadIdx.x;
  if (blockIdx.x >= NBLK1) {   // ---- init branch ----
    const int idx = (blockIdx.x - NBLK1) * 256 + t;
    const int n = idx >> 6, c = idx & 63;
    hb[idx] = (c < IN_C) ? bf16r(x[n * IN_C + c]) : (ushort)0;
    float acc = 0.0f;
#pragma unroll
    for (int k = 0; k < IN_C; ++k)
      acc = fmaf(bf16f(bf16r(x[n * IN_C + k])), bf16f(bf16r(Wg0[k * 64 + c])), acc);
    m16[idx] = bf16r(acc);
    if (idx < KTOT * HC) w1b[idx] = bf16r(W1[idx]);
    if (idx < 2 * 12288 + 4096) {   // GRU + Wg1 weights -> fragment layout
      int d = idx;
      if (d < 12288) {
        int j = d & 7, quad = (d >> 3) & 3, cc = (d >> 5) & 63,
            kh = (d >> 11) & 1, g3 = d >> 12;
        wihb[d] = bf16r(wih[(g3 * 64 + cc) * 64 + kh * 32 + quad * 8 + j]);
      } else if (d < 24576) {
        d -= 12288;
        int j = d & 7, quad = (d >> 3) & 3, cc = (d >> 5) & 63,
            kh = (d >> 11) & 1, g3 = d >> 12;
        whhb[d] = bf16r(whh[(g3 * 64 + cc) * 64 + kh * 32 + quad * 8 + j]);
      } else {
        d -= 24576;
        int j = d & 7, quad = (d >> 3) & 3, cc = (d >> 5) & 63, kh = d >> 11;
        wgnb[d] = bf16r(wgn[(kh * 32 + quad * 8 + j) * 64 + cc]);
      }
    }
    return;
  }
  // ---- partition branch ----
  const int blk = blockIdx.x;
  const int base = blk * CCHUNK;
  for (int i = t; i < NCB; i += 256) lhist[i] = 0;
  __syncthreads();
  for (int k = t; k < CCHUNK; k += 256)
    atomicAdd(&lhist[ei[NE + base + k] >> 8], 1);
  __syncthreads();
  int v0 = 0, v1 = 0;
  if (t < 160) { v0 = lhist[2 * t]; v1 = lhist[2 * t + 1]; }
  sc[t] = v0 + v1;
  __syncthreads();
  for (int d = 1; d < 256; d <<= 1) {
    int x2 = (t >= d) ? sc[t - d] : 0;
    __syncthreads();
    sc[t] += x2;
    __syncthreads();
  }
  if (t < 160) {
    int pref = sc[t] - v0 - v1;   // local exclusive prefix (LDS grouping base)
    int i0 = 2 * t, i1 = 2 * t + 1;
    int b0 = atomicAdd(&gcnt[i0], v0);   // slab offset within bucket i0
    int b1 = atomicAdd(&gcnt[i1], v1);
    lcur[i0] = pref;
    lcur[i1] = pref + v0;
    delta[i0] = i0 * SORTCAP + b0 - pref;
    delta[i1] = i1 * SORTCAP + b1 - (pref + v0);
  }
  __syncthreads();
  for (int k = t; k < CCHUNK; k += 256) {
    int e = base + k;
    int src = ei[e];
    int d = ei[NE + e];          // L2-hot re-read (saves LDS staging)
    ushort bw = bf16r(ea[e]);
    int slot = atomicAdd(&lcur[d >> 8], 1);
    lent[slot] = src | ((int)bw << 17);
    lkey[slot] = d;
  }
  __syncthreads();
  for (int k = t; k < CCHUNK; k += 256) {
    int d = lkey[k];
    int b = d >> 8;
    int g = delta[b] + k;
    if (g < (b + 1) * SORTCAP) {   // slab overflow guard (statistically never)
      ent4[g] = lent[k];
      dstlo[g] = (unsigned char)(d & 255);
    }
  }
}

// phase 2: per-bucket LDS counting sort -> node-sorted csr4 + off/cnt
__global__ void __launch_bounds__(256) k_sort(const int* __restrict__ ent4,
                                              const unsigned char* __restrict__ dstlo,
                                              const int* __restrict__ gcnt,
                                              int* __restrict__ csr4,
                                              int* __restrict__ off,
                                              int* __restrict__ cnt) {
  __shared__ int nh[256];
  __shared__ int part[256];
  __shared__ int sent[SORTCAP];
  const int t = threadIdx.x;
  const int b = blockIdx.x;
  const int r0 = b * SORTCAP;
  int len = gcnt[b];
  if (len > SORTCAP) len = SORTCAP;
  nh[t] = 0;
  __syncthreads();
  for (int k = t; k < len; k += 256) atomicAdd(&nh[dstlo[r0 + k]], 1);
  __syncthreads();
  int a0 = nh[t];
  part[t] = a0;
  __syncthreads();
  for (int d = 1; d < 256; d <<= 1) {
    int x2 = (t >= d) ? part[t - d] : 0;
    __syncthreads();
    part[t] += x2;
    __syncthreads();
  }
  const int base = part[t] - a0;
  const int n0 = b * 256;
  off[n0 + t] = r0 + base;
  cnt[n0 + t] = a0;
  nh[t] = base;
  __syncthreads();
  for (int k = t; k < len; k += 256) {
    int d = dstlo[r0 + k];
    int slot = atomicAdd(&nh[d], 1);
    sent[slot] = ent4[r0 + k];
  }
  __syncthreads();
  for (int k = t; k < len; k += 256) csr4[r0 + k] = sent[k];
}

// ---------------- per-layer kernels ----------------

// Paired-channel dual-node aggregate (line-rate bound at its measured
// roofline: 1.31M random 128B lines vs 4MB/XCD L2 -> L3-served floor).
__global__ void k_aggregate(const int* __restrict__ off, const int* __restrict__ cnt,
                            const int* __restrict__ csr4, const ushort* __restrict__ m16,
                            ushort* __restrict__ aggr16) {
  const int lane = threadIdx.x & 63;
  const int half = lane >> 5;
  const int cp = lane & 31;
  const uint* __restrict__ m32 = (const uint*)m16;
  uint* __restrict__ ag32 = (uint*)aggr16;
  const int wv = (blockIdx.x * 256 + threadIdx.x) >> 6;
  const int nw = (gridDim.x * 256) >> 6;
  const int stride = 2 * nw;
  int rA = 0, cAx = 0, eA = 0, rB = 0, cBx = 0, eB = 0;
  if (wv < NN) {
    rA = __builtin_amdgcn_readfirstlane(off[wv]);
    cAx = __builtin_amdgcn_readfirstlane(cnt[wv]);
    if (lane < cAx) eA = __builtin_nontemporal_load(csr4 + rA + lane);
    const int nB0 = wv + nw;
    if (nB0 < NN) {
      rB = __builtin_amdgcn_readfirstlane(off[nB0]);
      cBx = __builtin_amdgcn_readfirstlane(cnt[nB0]);
      if (lane < cBx) eB = __builtin_nontemporal_load(csr4 + rB + lane);
    }
  }
  for (int n = wv; n < NN; n += stride) {
    const int nB = n + nw;
    const int r0A = rA, cA = cAx, edA = eA;
    const int r0B = rB, cB = cBx, edB = eB;
    const int n2 = n + stride;
    if (n2 < NN) {
      rA = __builtin_amdgcn_readfirstlane(off[n2]);
      cAx = __builtin_amdgcn_readfirstlane(cnt[n2]);
      eA = 0;
      if (lane < cAx) eA = __builtin_nontemporal_load(csr4 + rA + lane);
      const int n2B = n2 + nw;
      eB = 0;
      cBx = 0;
      if (n2B < NN) {
        rB = __builtin_amdgcn_readfirstlane(off[n2B]);
        cBx = __builtin_amdgcn_readfirstlane(cnt[n2B]);
        if (lane < cBx) eB = __builtin_nontemporal_load(csr4 + rB + lane);
      }
    }
    const int ccA = cA > 64 ? 64 : cA;
    const int ccB = cB > 64 ? 64 : cB;
    const int ccM = ccA > ccB ? ccA : ccB;
    float aLo = 0.0f, aHi = 0.0f, bLo = 0.0f, bHi = 0.0f;
    for (int i = 0; i < ccM; i += 16) {   // 16 edges per node per iter, 16 loads
#pragma unroll
      for (int j = 0; j < 8; ++j) {
        const int s = i + 2 * j + half;
        const int xa = __shfl(edA, s, 64);
        const int xb = __shfl(edB, s, 64);
        const uint va = m32[(size_t)(xa & 0x1FFFF) * 32 + cp];
        const uint vb = m32[(size_t)(xb & 0x1FFFF) * 32 + cp];
        const float wA = __uint_as_float(((unsigned)xa >> 1) & 0xFFFF0000u);
        const float wB = __uint_as_float(((unsigned)xb >> 1) & 0xFFFF0000u);
        aLo = fmaf(__uint_as_float(va << 16), wA, aLo);
        aHi = fmaf(__uint_as_float(va & 0xFFFF0000u), wA, aHi);
        bLo = fmaf(__uint_as_float(vb << 16), wB, bLo);
        bHi = fmaf(__uint_as_float(vb & 0xFFFF0000u), wB, bHi);
      }
    }
    for (int j = 64; j < cA; ++j) {  // statistically impossible (row > 64)
      int x = csr4[r0A + j];
      if (half == 0) {
        uint v = m32[(size_t)(x & 0x1FFFF) * 32 + cp];
        float w = __uint_as_float(((unsigned)x >> 1) & 0xFFFF0000u);
        aLo = fmaf(__uint_as_float(v << 16), w, aLo);
        aHi = fmaf(__uint_as_float(v & 0xFFFF0000u), w, aHi);
      }
    }
    for (int j = 64; j < cB; ++j) {
      int x = csr4[r0B + j];
      if (half == 0) {
        uint v = m32[(size_t)(x & 0x1FFFF) * 32 + cp];
        float w = __uint_as_float(((unsigned)x >> 1) & 0xFFFF0000u);
        bLo = fmaf(__uint_as_float(v << 16), w, bLo);
        bHi = fmaf(__uint_as_float(v & 0xFFFF0000u), w, bHi);
      }
    }
    aLo += __shfl_xor(aLo, 32, 64);
    aHi += __shfl_xor(aHi, 32, 64);
    bLo += __shfl_xor(bLo, 32, 64);
    bHi += __shfl_xor(bHi, 32, 64);
    if (lane < 32) {
      ag32[(size_t)n * 32 + cp] = (uint)bf16r(aLo) | ((uint)bf16r(aHi) << 16);
      if (nB < NN)
        ag32[(size_t)nB * 32 + cp] = (uint)bf16r(bLo) | ((uint)bf16r(bHi) << 16);
    }
  }
}

// GRU via MFMA, ping-pong h (reads hbin, writes hbout). Weights pre-converted
// in fragment layout. Layer 0 fuses m = h_new @ Wg1 via a 2KB swizzled tile.
// Grid 2560 (2 group-iterations) — parallelism bump for the load-bound phases.
__global__ void __launch_bounds__(256) k_gru_mfma(
    const ushort* __restrict__ aggr16, const ushort* __restrict__ hbin,
    ushort* __restrict__ hbout,
    const ushort* __restrict__ wihb, const ushort* __restrict__ whhb,
    const float* __restrict__ bih, const float* __restrict__ bhh,
    const ushort* __restrict__ wgnb, ushort* __restrict__ m16) {
  __shared__ ushort ht[16 * 64];
  const int lane = threadIdx.x & 63;
  const int w = threadIdx.x >> 6;
  const int cl = lane & 15;
  const int quad = lane >> 4;
  const int c = w * 16 + cl;

  bf16x8 BI[3][2], BH[3][2];
#pragma unroll
  for (int g3 = 0; g3 < 3; ++g3)
#pragma unroll
    for (int kh = 0; kh < 2; ++kh) {
      const size_t fo = (size_t)((((g3 * 2 + kh) * 64 + c) * 4 + quad)) * 8;
      BI[g3][kh] = *(const bf16x8*)(wihb + fo);
      BH[g3][kh] = *(const bf16x8*)(whhb + fo);
    }
  bf16x8 B2[2];
  if (wgnb) {
#pragma unroll
    for (int kh = 0; kh < 2; ++kh)
      B2[kh] = *(const bf16x8*)(wgnb + (size_t)(((kh * 64 + c) * 4 + quad)) * 8);
  }
  const float br = bih[c] + bhh[c];
  const float bz = bih[64 + c] + bhh[64 + c];
  const float bni = bih[128 + c];
  const float bnh = bhh[128 + c];

  const int ngroups = NN / 16;  // 5120
  for (int g = blockIdx.x; g < ngroups; g += gridDim.x) {
    const size_t arow = (size_t)(g * 16 + cl) * 64 + quad * 8;
    bf16x8 a0 = *(const bf16x8*)(aggr16 + arow);
    bf16x8 a1 = *(const bf16x8*)(aggr16 + arow + 32);
    bf16x8 h0 = *(const bf16x8*)(hbin + arow);
    bf16x8 h1 = *(const bf16x8*)(hbin + arow + 32);
    float hv[4];
    const size_t obase = (size_t)(g * 16 + quad * 4) * 64 + c;
#pragma unroll
    for (int rg = 0; rg < 4; ++rg) hv[rg] = bf16f(hbin[obase + (size_t)rg * 64]);

    f32x4 zero = {0.0f, 0.0f, 0.0f, 0.0f};
    f32x4 aR = zero, aZ = zero, aN = zero, hR = zero, hZ = zero, hN = zero;
    aR = __builtin_amdgcn_mfma_f32_16x16x32_bf16(a0, BI[0][0], aR, 0, 0, 0);
    aR = __builtin_amdgcn_mfma_f32_16x16x32_bf16(a1, BI[0][1], aR, 0, 0, 0);
    aZ = __builtin_amdgcn_mfma_f32_16x16x32_bf16(a0, BI[1][0], aZ, 0, 0, 0);
    aZ = __builtin_amdgcn_mfma_f32_16x16x32_bf16(a1, BI[1][1], aZ, 0, 0, 0);
    aN = __builtin_amdgcn_mfma_f32_16x16x32_bf16(a0, BI[2][0], aN, 0, 0, 0);
    aN = __builtin_amdgcn_mfma_f32_16x16x32_bf16(a1, BI[2][1], aN, 0, 0, 0);
    hR = __builtin_amdgcn_mfma_f32_16x16x32_bf16(h0, BH[0][0], hR, 0, 0, 0);
    hR = __builtin_amdgcn_mfma_f32_16x16x32_bf16(h1, BH[0][1], hR, 0, 0, 0);
    hZ = __builtin_amdgcn_mfma_f32_16x16x32_bf16(h0, BH[1][0], hZ, 0, 0, 0);
    hZ = __builtin_amdgcn_mfma_f32_16x16x32_bf16(h1, BH[1][1], hZ, 0, 0, 0);
    hN = __builtin_amdgcn_mfma_f32_16x16x32_bf16(h0, BH[2][0], hN, 0, 0, 0);
    hN = __builtin_amdgcn_mfma_f32_16x16x32_bf16(h1, BH[2][1], hN, 0, 0, 0);

#pragma unroll
    for (int rg = 0; rg < 4; ++rg) {
      float r = sigmoidf_(aR[rg] + hR[rg] + br);
      float z = sigmoidf_(aZ[rg] + hZ[rg] + bz);
      float nv = tanhf_(aN[rg] + bni + r * (hN[rg] + bnh));
      ushort hn = bf16r((1.0f - z) * nv + z * hv[rg]);
      hbout[obase + (size_t)rg * 64] = hn;
      if (wgnb) {
        const int row = quad * 4 + rg;
        ht[(row * 64 + c) ^ ((row & 7) << 3)] = hn;  // XOR-swizzled (G4)
      }
    }
    if (wgnb) {
      __syncthreads();  // h-tile fully in LDS
      bf16x8 A0 = *(const bf16x8*)&ht[(cl * 64 + quad * 8) ^ ((cl & 7) << 3)];
      bf16x8 A1 = *(const bf16x8*)&ht[(cl * 64 + 32 + quad * 8) ^ ((cl & 7) << 3)];
      f32x4 mz = {0.0f, 0.0f, 0.0f, 0.0f};
      mz = __builtin_amdgcn_mfma_f32_16x16x32_bf16(A0, B2[0], mz, 0, 0, 0);
      mz = __builtin_amdgcn_mfma_f32_16x16x32_bf16(A1, B2[1], mz, 0, 0, 0);
#pragma unroll
      for (int rg = 0; rg < 4; ++rg)
        m16[(size_t)(g * 16 + quad * 4 + rg) * 64 + c] = bf16r(mz[rg]);
      __syncthreads();  // LDS reads done before next iteration overwrites ht
    }
  }
}

// MLP1 via MFMA, 32-way K split (one electrode per slice): 1024 blocks =
// 4096 waves (2x parallelism), 10 MFMAs each.
// part[sl][bs][c] = sum_g A(:, g, e=sl, :) @ W1.T-slice
__global__ void __launch_bounds__(256) k_mlp1_mfma(
    const ushort* __restrict__ hb, const ushort* __restrict__ w1b,
    float* __restrict__ part) {
  const int lane = threadIdx.x & 63;
  const int w = threadIdx.x >> 6;
  const int cl = lane & 15;
  const int quad = lane >> 4;
  const int bg = blockIdx.x >> 5;
  const int sl = blockIdx.x & 31;
  const int bs0 = bg * 16;
  const int c = w * 16 + cl;
  const int e = sl;
  f32x4 acc = {0.0f, 0.0f, 0.0f, 0.0f};
#pragma unroll
  for (int g = 0; g < 5; ++g) {
    const ushort* hp = hb + ((size_t)(bs0 + cl) * 160 + g * 32 + e) * 64 + quad * 8;
    bf16x8 a0 = *(const bf16x8*)hp;
    bf16x8 a1 = *(const bf16x8*)(hp + 32);
    const int kbase = e * 320 + g * 64;
    const ushort* wp = w1b + (size_t)c * KTOT + kbase + quad * 8;
    bf16x8 b0 = *(const bf16x8*)wp;
    bf16x8 b1 = *(const bf16x8*)(wp + 32);
    acc = __builtin_amdgcn_mfma_f32_16x16x32_bf16(a0, b0, acc, 0, 0, 0);
    acc = __builtin_amdgcn_mfma_f32_16x16x32_bf16(a1, b1, acc, 0, 0, 0);
  }
  float* pp = part + ((size_t)sl * BSZ + bs0 + quad * 4) * 64 + c;
#pragma unroll
  for (int rg = 0; rg < 4; ++rg) pp[(size_t)rg * 64] = acc[rg];
}

// sum 32 slice-partials, +b1, relu -> 32 -> 16 -> 3 -> softmax; wave-per-row
__global__ void k_tail(const float* __restrict__ part, const float* __restrict__ b1,
                       const float* __restrict__ W2, const float* __restrict__ b2,
                       const float* __restrict__ W3, const float* __restrict__ b3,
                       const float* __restrict__ W4, const float* __restrict__ b4,
                       float* __restrict__ out) {
  const int lane = threadIdx.x & 63;
  const int bs = blockIdx.x * 4 + (threadIdx.x >> 6);
  float zp = 0.0f;
#pragma unroll
  for (int s = 0; s < NSLICE; ++s) zp += part[((size_t)s * BSZ + bs) * 64 + lane];
  float zv = fmaxf(zp + b1[lane], 0.0f);
  const int c2 = lane & 31;
  float acc2 = b2[c2];
#pragma unroll
  for (int k = 0; k < 64; ++k) acc2 = fmaf(bcast(zv, k), W2[c2 * 64 + k], acc2);
  acc2 = fmaxf(acc2, 0.0f);
  const int c3 = lane & 15;
  float acc3 = b3[c3];
#pragma unroll
  for (int k = 0; k < 32; ++k) acc3 = fmaf(bcast(acc2, k), W3[c3 * 32 + k], acc3);
  acc3 = fmaxf(acc3, 0.0f);
  float l0 = b4[0], l1 = b4[1], l2 = b4[2];
#pragma unroll
  for (int k = 0; k < 16; ++k) {
    float v = bcast(acc3, k);
    l0 = fmaf(v, W4[k], l0);
    l1 = fmaf(v, W4[16 + k], l1);
    l2 = fmaf(v, W4[32 + k], l2);
  }
  float mx = fmaxf(l0, fmaxf(l1, l2));
  float e0 = __expf(l0 - mx), e1 = __expf(l1 - mx), e2 = __expf(l2 - mx);
  float inv = 1.0f / (e0 + e1 + e2);
  if (lane == 0) {
    out[bs * 3 + 0] = e0 * inv;
    out[bs * 3 + 1] = e1 * inv;
    out[bs * 3 + 2] = e2 * inv;
  }
}

extern "C" void kernel_launch(void* const* d_in, const int* in_sizes, int n_in,
                              void* d_out, int out_size, void* d_ws, size_t ws_size,
                              hipStream_t stream) {
  const float* x = (const float*)d_in[0];
  const int* ei = (const int*)d_in[1];
  const float* ea = (const float*)d_in[2];
  const float* Wg = (const float*)d_in[3];
  const float* wih = (const float*)d_in[4];
  const float* whh = (const float*)d_in[5];
  const float* bih = (const float*)d_in[6];
  const float* bhh = (const float*)d_in[7];
  const float* W1 = (const float*)d_in[8];
  const float* b1 = (const float*)d_in[9];
  const float* W2 = (const float*)d_in[10];
  const float* b2 = (const float*)d_in[11];
  const float* W3 = (const float*)d_in[12];
  const float* b3 = (const float*)d_in[13];
  const float* W4 = (const float*)d_in[14];
  const float* b4 = (const float*)d_in[15];
  float* out = (float*)d_out;

  // workspace layout (descending alignment: f32/int, then ushort, then uchar)
  float* part = (float*)d_ws;                           // NSLICE*BSZ*64 f32
  int* gcnt = (int*)(part + (size_t)NSLICE * BSZ * 64); // NCB (pad to 384)
  int* off = gcnt + 384;                                // NN
  int* cnt = off + NN;                                  // NN
  int* ent4 = cnt + NN;                                 // NCB*SORTCAP
  int* csr4 = ent4 + (size_t)NCB * SORTCAP;             // NCB*SORTCAP
  ushort* hba = (ushort*)(csr4 + (size_t)NCB * SORTCAP);// NN*64 (ping)
  ushort* hbb = hba + (size_t)NN * 64;                  // NN*64 (pong)
  ushort* m16 = hbb + (size_t)NN * 64;                  // NN*64 (row-major)
  ushort* aggr16 = m16 + (size_t)NN * 64;               // NN*64
  ushort* w1b = aggr16 + (size_t)NN * 64;               // KTOT*HC
  ushort* wihb = w1b + (size_t)KTOT * HC;               // 12288
  ushort* whhb = wihb + 12288;                          // 12288
  ushort* wgnb = whhb + 12288;                          // 4096
  unsigned char* dstlo = (unsigned char*)(wgnb + 4096); // NCB*SORTCAP

  // --- build: partition fused with init (640 + 20480 blocks), then sort ---
  hipMemsetAsync(gcnt, 0, NCB * sizeof(int), stream);
  k_part1<<<NBLK1 + INITB, 256, 0, stream>>>(ei, ea, gcnt, ent4, dstlo,
                                             x, Wg, hba, m16, W1, w1b,
                                             wih, whh, Wg + 64 * 64,
                                             wihb, whhb, wgnb);
  k_sort<<<NCB, 256, 0, stream>>>(ent4, dstlo, gcnt, csr4, off, cnt);

  // layer 0 (gru fuses m = h1 @ Wg[1] for layer 1); h ping-pongs hba->hbb->hba
  k_aggregate<<<2048, 256, 0, stream>>>(off, cnt, csr4, m16, aggr16);
  k_gru_mfma<<<2560, 256, 0, stream>>>(aggr16, hba, hbb, wihb, whhb, bih, bhh,
                                       wgnb, m16);
  // layer 1
  k_aggregate<<<2048, 256, 0, stream>>>(off, cnt, csr4, m16, aggr16);
  k_gru_mfma<<<2560, 256, 0, stream>>>(aggr16, hbb, hba, wihb, whhb, bih, bhh,
                                       nullptr, m16);
  k_mlp1_mfma<<<1024, 256, 0, stream>>>(hba, w1b, part);
  k_tail<<<BSZ / 4, 256, 0, stream>>>(part, b1, W2, b2, W3, b3, W4, b4, out);
}

// Round 10
// 282.189 us; speedup vs baseline: 1.0346x; 1.0346x over previous
//
#include <hip/hip_runtime.h>
#include <cstdint>

#define BSZ 512
#define NG 5
#define NEL 32
#define IN_C 5
#define HC 64
#define NN (BSZ * NG * NEL)   // 81920 nodes
#define NE (NN * 16)          // 1310720 edges
#define NC 3
#define KTOT (NG * NEL * HC)  // 10240
#define NSLICE 16
#define NCB 320               // coarse buckets (256 nodes each, dst>>8)
#define CCHUNK 2048           // edges per partition block (640 blocks; measured optimum)
#define NBLK1 (NE / CCHUNK)   // 640
#define SORTCAP 5120          // fixed bucket slab capacity (avg 4096, +16 sigma)
#define INITB (NN * 64 / 256) // 20480 init blocks fused into part1

typedef __attribute__((ext_vector_type(8))) short bf16x8;
typedef __attribute__((ext_vector_type(4))) float f32x4;

__device__ __forceinline__ float bcast(float v, int l) {
  return __int_as_float(__builtin_amdgcn_readlane(__float_as_int(v), l));
}

__device__ __forceinline__ ushort bf16r(float f) {   // RNE f32->bf16
  unsigned u = __float_as_uint(f);
  return (ushort)((u + 0x7FFFu + ((u >> 16) & 1u)) >> 16);
}

__device__ __forceinline__ float bf16f(ushort s) {
  return __uint_as_float(((unsigned)s) << 16);
}

__device__ __forceinline__ float sigmoidf_(float x) {
  return 1.0f / (1.0f + __expf(-x));
}

__device__ __forceinline__ float tanhf_(float x) {
  x = fminf(fmaxf(x, -15.0f), 15.0f);
  float e = __expf(2.0f * x);
  return (e - 1.0f) / (e + 1.0f);
}

// ---------------- fused partition + init ----------------
// Blocks [0,NBLK1): one-phase partition into fixed-capacity bucket slabs
//   (CCHUNK=2048: measured optimum — 1024 doubled per-block fixed cost,
//   4096 halved block parallelism; both measured slower).
// Blocks [NBLK1, ...): init — hb, layer-0 m16 (5 nonzero K-cols collapse the
//   GEMM to 5 FMAs), W1->bf16, GRU/Wg1 weights -> fragment layout.
__global__ void __launch_bounds__(256) k_part1(
    const int* __restrict__ ei, const float* __restrict__ ea,
    int* __restrict__ gcnt, int* __restrict__ ent4,
    unsigned char* __restrict__ dstlo,
    const float* __restrict__ x, const float* __restrict__ Wg0,
    ushort* __restrict__ hb, ushort* __restrict__ m16,
    const float* __restrict__ W1, ushort* __restrict__ w1b,
    const float* __restrict__ wih, const float* __restrict__ whh,
    const float* __restrict__ wgn,
    ushort* __restrict__ wihb, ushort* __restrict__ whhb,
    ushort* __restrict__ wgnb) {
  __shared__ int lent[CCHUNK];   // 8 KB
  __shared__ int lkey[CCHUNK];   // 8 KB
  __shared__ int lhist[NCB];
  __shared__ int lcur[NCB];
  __shared__ int delta[NCB];
  __shared__ int sc[256];
  const int t = threadIdx.x;
  if (blockIdx.x >= NBLK1) {   // ---- init branch ----
    const int idx = (blockIdx.x - NBLK1) * 256 + t;
    const int n = idx >> 6, c = idx & 63;
    hb[idx] = (c < IN_C) ? bf16r(x[n * IN_C + c]) : (ushort)0;
    float acc = 0.0f;
#pragma unroll
    for (int k = 0; k < IN_C; ++k)
      acc = fmaf(bf16f(bf16r(x[n * IN_C + k])), bf16f(bf16r(Wg0[k * 64 + c])), acc);
    m16[idx] = bf16r(acc);
    if (idx < KTOT * HC) w1b[idx] = bf16r(W1[idx]);
    if (idx < 2 * 12288 + 4096) {   // GRU + Wg1 weights -> fragment layout
      int d = idx;
      if (d < 12288) {
        int j = d & 7, quad = (d >> 3) & 3, cc = (d >> 5) & 63,
            kh = (d >> 11) & 1, g3 = d >> 12;
        wihb[d] = bf16r(wih[(g3 * 64 + cc) * 64 + kh * 32 + quad * 8 + j]);
      } else if (d < 24576) {
        d -= 12288;
        int j = d & 7, quad = (d >> 3) & 3, cc = (d >> 5) & 63,
            kh = (d >> 11) & 1, g3 = d >> 12;
        whhb[d] = bf16r(whh[(g3 * 64 + cc) * 64 + kh * 32 + quad * 8 + j]);
      } else {
        d -= 24576;
        int j = d & 7, quad = (d >> 3) & 3, cc = (d >> 5) & 63, kh = d >> 11;
        wgnb[d] = bf16r(wgn[(kh * 32 + quad * 8 + j) * 64 + cc]);
      }
    }
    return;
  }
  // ---- partition branch ----
  const int blk = blockIdx.x;
  const int base = blk * CCHUNK;
  for (int i = t; i < NCB; i += 256) lhist[i] = 0;
  __syncthreads();
  for (int k = t; k < CCHUNK; k += 256)
    atomicAdd(&lhist[ei[NE + base + k] >> 8], 1);
  __syncthreads();
  int v0 = 0, v1 = 0;
  if (t < 160) { v0 = lhist[2 * t]; v1 = lhist[2 * t + 1]; }
  sc[t] = v0 + v1;
  __syncthreads();
  for (int d = 1; d < 256; d <<= 1) {
    int x2 = (t >= d) ? sc[t - d] : 0;
    __syncthreads();
    sc[t] += x2;
    __syncthreads();
  }
  if (t < 160) {
    int pref = sc[t] - v0 - v1;   // local exclusive prefix (LDS grouping base)
    int i0 = 2 * t, i1 = 2 * t + 1;
    int b0 = atomicAdd(&gcnt[i0], v0);   // slab offset within bucket i0
    int b1 = atomicAdd(&gcnt[i1], v1);
    lcur[i0] = pref;
    lcur[i1] = pref + v0;
    delta[i0] = i0 * SORTCAP + b0 - pref;
    delta[i1] = i1 * SORTCAP + b1 - (pref + v0);
  }
  __syncthreads();
  for (int k = t; k < CCHUNK; k += 256) {
    int e = base + k;
    int src = ei[e];
    int d = ei[NE + e];          // L2-hot re-read (saves LDS staging)
    ushort bw = bf16r(ea[e]);
    int slot = atomicAdd(&lcur[d >> 8], 1);
    lent[slot] = src | ((int)bw << 17);
    lkey[slot] = d;
  }
  __syncthreads();
  for (int k = t; k < CCHUNK; k += 256) {
    int d = lkey[k];
    int b = d >> 8;
    int g = delta[b] + k;
    if (g < (b + 1) * SORTCAP) {   // slab overflow guard (statistically never)
      ent4[g] = lent[k];
      dstlo[g] = (unsigned char)(d & 255);
    }
  }
}

// phase 2: per-bucket LDS counting sort -> node-sorted csr4 + off/cnt
__global__ void __launch_bounds__(256) k_sort(const int* __restrict__ ent4,
                                              const unsigned char* __restrict__ dstlo,
                                              const int* __restrict__ gcnt,
                                              int* __restrict__ csr4,
                                              int* __restrict__ off,
                                              int* __restrict__ cnt) {
  __shared__ int nh[256];
  __shared__ int part[256];
  __shared__ int sent[SORTCAP];
  const int t = threadIdx.x;
  const int b = blockIdx.x;
  const int r0 = b * SORTCAP;
  int len = gcnt[b];
  if (len > SORTCAP) len = SORTCAP;
  nh[t] = 0;
  __syncthreads();
  for (int k = t; k < len; k += 256) atomicAdd(&nh[dstlo[r0 + k]], 1);
  __syncthreads();
  int a0 = nh[t];
  part[t] = a0;
  __syncthreads();
  for (int d = 1; d < 256; d <<= 1) {
    int x2 = (t >= d) ? part[t - d] : 0;
    __syncthreads();
    part[t] += x2;
    __syncthreads();
  }
  const int base = part[t] - a0;
  const int n0 = b * 256;
  off[n0 + t] = r0 + base;
  cnt[n0 + t] = a0;
  nh[t] = base;
  __syncthreads();
  for (int k = t; k < len; k += 256) {
    int d = dstlo[r0 + k];
    int slot = atomicAdd(&nh[d], 1);
    sent[slot] = ent4[r0 + k];
  }
  __syncthreads();
  for (int k = t; k < len; k += 256) csr4[r0 + k] = sent[k];
}

// ---------------- per-layer kernels ----------------

// Paired-channel dual-node aggregate (line-rate bound at its measured
// roofline: 1.31M random 128B lines vs 4MB/XCD L2 -> L3-served floor).
__global__ void k_aggregate(const int* __restrict__ off, const int* __restrict__ cnt,
                            const int* __restrict__ csr4, const ushort* __restrict__ m16,
                            ushort* __restrict__ aggr16) {
  const int lane = threadIdx.x & 63;
  const int half = lane >> 5;
  const int cp = lane & 31;
  const uint* __restrict__ m32 = (const uint*)m16;
  uint* __restrict__ ag32 = (uint*)aggr16;
  const int wv = (blockIdx.x * 256 + threadIdx.x) >> 6;
  const int nw = (gridDim.x * 256) >> 6;
  const int stride = 2 * nw;
  int rA = 0, cAx = 0, eA = 0, rB = 0, cBx = 0, eB = 0;
  if (wv < NN) {
    rA = __builtin_amdgcn_readfirstlane(off[wv]);
    cAx = __builtin_amdgcn_readfirstlane(cnt[wv]);
    if (lane < cAx) eA = __builtin_nontemporal_load(csr4 + rA + lane);
    const int nB0 = wv + nw;
    if (nB0 < NN) {
      rB = __builtin_amdgcn_readfirstlane(off[nB0]);
      cBx = __builtin_amdgcn_readfirstlane(cnt[nB0]);
      if (lane < cBx) eB = __builtin_nontemporal_load(csr4 + rB + lane);
    }
  }
  for (int n = wv; n < NN; n += stride) {
    const int nB = n + nw;
    const int r0A = rA, cA = cAx, edA = eA;
    const int r0B = rB, cB = cBx, edB = eB;
    const int n2 = n + stride;
    if (n2 < NN) {
      rA = __builtin_amdgcn_readfirstlane(off[n2]);
      cAx = __builtin_amdgcn_readfirstlane(cnt[n2]);
      eA = 0;
      if (lane < cAx) eA = __builtin_nontemporal_load(csr4 + rA + lane);
      const int n2B = n2 + nw;
      eB = 0;
      cBx = 0;
      if (n2B < NN) {
        rB = __builtin_amdgcn_readfirstlane(off[n2B]);
        cBx = __builtin_amdgcn_readfirstlane(cnt[n2B]);
        if (lane < cBx) eB = __builtin_nontemporal_load(csr4 + rB + lane);
      }
    }
    const int ccA = cA > 64 ? 64 : cA;
    const int ccB = cB > 64 ? 64 : cB;
    const int ccM = ccA > ccB ? ccA : ccB;
    float aLo = 0.0f, aHi = 0.0f, bLo = 0.0f, bHi = 0.0f;
    for (int i = 0; i < ccM; i += 16) {   // 16 edges per node per iter, 16 loads
#pragma unroll
      for (int j = 0; j < 8; ++j) {
        const int s = i + 2 * j + half;
        const int xa = __shfl(edA, s, 64);
        const int xb = __shfl(edB, s, 64);
        const uint va = m32[(size_t)(xa & 0x1FFFF) * 32 + cp];
        const uint vb = m32[(size_t)(xb & 0x1FFFF) * 32 + cp];
        const float wA = __uint_as_float(((unsigned)xa >> 1) & 0xFFFF0000u);
        const float wB = __uint_as_float(((unsigned)xb >> 1) & 0xFFFF0000u);
        aLo = fmaf(__uint_as_float(va << 16), wA, aLo);
        aHi = fmaf(__uint_as_float(va & 0xFFFF0000u), wA, aHi);
        bLo = fmaf(__uint_as_float(vb << 16), wB, bLo);
        bHi = fmaf(__uint_as_float(vb & 0xFFFF0000u), wB, bHi);
      }
    }
    for (int j = 64; j < cA; ++j) {  // statistically impossible (row > 64)
      int x = csr4[r0A + j];
      if (half == 0) {
        uint v = m32[(size_t)(x & 0x1FFFF) * 32 + cp];
        float w = __uint_as_float(((unsigned)x >> 1) & 0xFFFF0000u);
        aLo = fmaf(__uint_as_float(v << 16), w, aLo);
        aHi = fmaf(__uint_as_float(v & 0xFFFF0000u), w, aHi);
      }
    }
    for (int j = 64; j < cB; ++j) {
      int x = csr4[r0B + j];
      if (half == 0) {
        uint v = m32[(size_t)(x & 0x1FFFF) * 32 + cp];
        float w = __uint_as_float(((unsigned)x >> 1) & 0xFFFF0000u);
        bLo = fmaf(__uint_as_float(v << 16), w, bLo);
        bHi = fmaf(__uint_as_float(v & 0xFFFF0000u), w, bHi);
      }
    }
    aLo += __shfl_xor(aLo, 32, 64);
    aHi += __shfl_xor(aHi, 32, 64);
    bLo += __shfl_xor(bLo, 32, 64);
    bHi += __shfl_xor(bHi, 32, 64);
    if (lane < 32) {
      ag32[(size_t)n * 32 + cp] = (uint)bf16r(aLo) | ((uint)bf16r(aHi) << 16);
      if (nB < NN)
        ag32[(size_t)nB * 32 + cp] = (uint)bf16r(bLo) | ((uint)bf16r(bHi) << 16);
    }
  }
}

// GRU via MFMA, ping-pong h (reads hbin, writes hbout). Weights pre-converted
// in fragment layout. Layer 0 fuses m = h_new @ Wg1 via a 2KB swizzled tile.
__global__ void __launch_bounds__(256) k_gru_mfma(
    const ushort* __restrict__ aggr16, const ushort* __restrict__ hbin,
    ushort* __restrict__ hbout,
    const ushort* __restrict__ wihb, const ushort* __restrict__ whhb,
    const float* __restrict__ bih, const float* __restrict__ bhh,
    const ushort* __restrict__ wgnb, ushort* __restrict__ m16) {
  __shared__ ushort ht[16 * 64];
  const int lane = threadIdx.x & 63;
  const int w = threadIdx.x >> 6;
  const int cl = lane & 15;
  const int quad = lane >> 4;
  const int c = w * 16 + cl;

  bf16x8 BI[3][2], BH[3][2];
#pragma unroll
  for (int g3 = 0; g3 < 3; ++g3)
#pragma unroll
    for (int kh = 0; kh < 2; ++kh) {
      const size_t fo = (size_t)((((g3 * 2 + kh) * 64 + c) * 4 + quad)) * 8;
      BI[g3][kh] = *(const bf16x8*)(wihb + fo);
      BH[g3][kh] = *(const bf16x8*)(whhb + fo);
    }
  bf16x8 B2[2];
  if (wgnb) {
#pragma unroll
    for (int kh = 0; kh < 2; ++kh)
      B2[kh] = *(const bf16x8*)(wgnb + (size_t)(((kh * 64 + c) * 4 + quad)) * 8);
  }
  const float br = bih[c] + bhh[c];
  const float bz = bih[64 + c] + bhh[64 + c];
  const float bni = bih[128 + c];
  const float bnh = bhh[128 + c];

  const int ngroups = NN / 16;  // 5120
  for (int g = blockIdx.x; g < ngroups; g += gridDim.x) {
    const size_t arow = (size_t)(g * 16 + cl) * 64 + quad * 8;
    bf16x8 a0 = *(const bf16x8*)(aggr16 + arow);
    bf16x8 a1 = *(const bf16x8*)(aggr16 + arow + 32);
    bf16x8 h0 = *(const bf16x8*)(hbin + arow);
    bf16x8 h1 = *(const bf16x8*)(hbin + arow + 32);
    float hv[4];
    const size_t obase = (size_t)(g * 16 + quad * 4) * 64 + c;
#pragma unroll
    for (int rg = 0; rg < 4; ++rg) hv[rg] = bf16f(hbin[obase + (size_t)rg * 64]);

    f32x4 zero = {0.0f, 0.0f, 0.0f, 0.0f};
    f32x4 aR = zero, aZ = zero, aN = zero, hR = zero, hZ = zero, hN = zero;
    aR = __builtin_amdgcn_mfma_f32_16x16x32_bf16(a0, BI[0][0], aR, 0, 0, 0);
    aR = __builtin_amdgcn_mfma_f32_16x16x32_bf16(a1, BI[0][1], aR, 0, 0, 0);
    aZ = __builtin_amdgcn_mfma_f32_16x16x32_bf16(a0, BI[1][0], aZ, 0, 0, 0);
    aZ = __builtin_amdgcn_mfma_f32_16x16x32_bf16(a1, BI[1][1], aZ, 0, 0, 0);
    aN = __builtin_amdgcn_mfma_f32_16x16x32_bf16(a0, BI[2][0], aN, 0, 0, 0);
    aN = __builtin_amdgcn_mfma_f32_16x16x32_bf16(a1, BI[2][1], aN, 0, 0, 0);
    hR = __builtin_amdgcn_mfma_f32_16x16x32_bf16(h0, BH[0][0], hR, 0, 0, 0);
    hR = __builtin_amdgcn_mfma_f32_16x16x32_bf16(h1, BH[0][1], hR, 0, 0, 0);
    hZ = __builtin_amdgcn_mfma_f32_16x16x32_bf16(h0, BH[1][0], hZ, 0, 0, 0);
    hZ = __builtin_amdgcn_mfma_f32_16x16x32_bf16(h1, BH[1][1], hZ, 0, 0, 0);
    hN = __builtin_amdgcn_mfma_f32_16x16x32_bf16(h0, BH[2][0], hN, 0, 0, 0);
    hN = __builtin_amdgcn_mfma_f32_16x16x32_bf16(h1, BH[2][1], hN, 0, 0, 0);

#pragma unroll
    for (int rg = 0; rg < 4; ++rg) {
      float r = sigmoidf_(aR[rg] + hR[rg] + br);
      float z = sigmoidf_(aZ[rg] + hZ[rg] + bz);
      float nv = tanhf_(aN[rg] + bni + r * (hN[rg] + bnh));
      ushort hn = bf16r((1.0f - z) * nv + z * hv[rg]);
      hbout[obase + (size_t)rg * 64] = hn;
      if (wgnb) {
        const int row = quad * 4 + rg;
        ht[(row * 64 + c) ^ ((row & 7) << 3)] = hn;  // XOR-swizzled (G4)
      }
    }
    if (wgnb) {
      __syncthreads();  // h-tile fully in LDS
      bf16x8 A0 = *(const bf16x8*)&ht[(cl * 64 + quad * 8) ^ ((cl & 7) << 3)];
      bf16x8 A1 = *(const bf16x8*)&ht[(cl * 64 + 32 + quad * 8) ^ ((cl & 7) << 3)];
      f32x4 mz = {0.0f, 0.0f, 0.0f, 0.0f};
      mz = __builtin_amdgcn_mfma_f32_16x16x32_bf16(A0, B2[0], mz, 0, 0, 0);
      mz = __builtin_amdgcn_mfma_f32_16x16x32_bf16(A1, B2[1], mz, 0, 0, 0);
#pragma unroll
      for (int rg = 0; rg < 4; ++rg)
        m16[(size_t)(g * 16 + quad * 4 + rg) * 64 + c] = bf16r(mz[rg]);
      __syncthreads();  // LDS reads done before next iteration overwrites ht
    }
  }
}

// MLP1 via MFMA: part[sl][bs][c] = A-slice @ W1.T-slice (all-bf16 inputs)
__global__ void __launch_bounds__(256) k_mlp1_mfma(
    const ushort* __restrict__ hb, const ushort* __restrict__ w1b,
    float* __restrict__ part) {
  const int lane = threadIdx.x & 63;
  const int w = threadIdx.x >> 6;
  const int cl = lane & 15;
  const int quad = lane >> 4;
  const int bg = blockIdx.x >> 4;
  const int sl = blockIdx.x & 15;
  const int bs0 = bg * 16;
  const int c = w * 16 + cl;
  f32x4 acc = {0.0f, 0.0f, 0.0f, 0.0f};
#pragma unroll
  for (int e2 = 0; e2 < 2; ++e2) {
    const int e = sl * 2 + e2;
#pragma unroll
    for (int g = 0; g < 5; ++g) {
      const ushort* hp = hb + ((size_t)(bs0 + cl) * 160 + g * 32 + e) * 64 + quad * 8;
      bf16x8 a0 = *(const bf16x8*)hp;
      bf16x8 a1 = *(const bf16x8*)(hp + 32);
      const int kbase = e * 320 + g * 64;
      const ushort* wp = w1b + (size_t)c * KTOT + kbase + quad * 8;
      bf16x8 b0 = *(const bf16x8*)wp;
      bf16x8 b1 = *(const bf16x8*)(wp + 32);
      acc = __builtin_amdgcn_mfma_f32_16x16x32_bf16(a0, b0, acc, 0, 0, 0);
      acc = __builtin_amdgcn_mfma_f32_16x16x32_bf16(a1, b1, acc, 0, 0, 0);
    }
  }
  float* pp = part + ((size_t)sl * BSZ + bs0 + quad * 4) * 64 + c;
#pragma unroll
  for (int rg = 0; rg < 4; ++rg) pp[(size_t)rg * 64] = acc[rg];
}

// sum 16 slice-partials, +b1, relu -> 32 -> 16 -> 3 -> softmax; wave-per-row
__global__ void k_tail(const float* __restrict__ part, const float* __restrict__ b1,
                       const float* __restrict__ W2, const float* __restrict__ b2,
                       const float* __restrict__ W3, const float* __restrict__ b3,
                       const float* __restrict__ W4, const float* __restrict__ b4,
                       float* __restrict__ out) {
  const int lane = threadIdx.x & 63;
  const int bs = blockIdx.x * 4 + (threadIdx.x >> 6);
  float zp = 0.0f;
#pragma unroll
  for (int s = 0; s < NSLICE; ++s) zp += part[((size_t)s * BSZ + bs) * 64 + lane];
  float zv = fmaxf(zp + b1[lane], 0.0f);
  const int c2 = lane & 31;
  float acc2 = b2[c2];
#pragma unroll
  for (int k = 0; k < 64; ++k) acc2 = fmaf(bcast(zv, k), W2[c2 * 64 + k], acc2);
  acc2 = fmaxf(acc2, 0.0f);
  const int c3 = lane & 15;
  float acc3 = b3[c3];
#pragma unroll
  for (int k = 0; k < 32; ++k) acc3 = fmaf(bcast(acc2, k), W3[c3 * 32 + k], acc3);
  acc3 = fmaxf(acc3, 0.0f);
  float l0 = b4[0], l1 = b4[1], l2 = b4[2];
#pragma unroll
  for (int k = 0; k < 16; ++k) {
    float v = bcast(acc3, k);
    l0 = fmaf(v, W4[k], l0);
    l1 = fmaf(v, W4[16 + k], l1);
    l2 = fmaf(v, W4[32 + k], l2);
  }
  float mx = fmaxf(l0, fmaxf(l1, l2));
  float e0 = __expf(l0 - mx), e1 = __expf(l1 - mx), e2 = __expf(l2 - mx);
  float inv = 1.0f / (e0 + e1 + e2);
  if (lane == 0) {
    out[bs * 3 + 0] = e0 * inv;
    out[bs * 3 + 1] = e1 * inv;
    out[bs * 3 + 2] = e2 * inv;
  }
}

extern "C" void kernel_launch(void* const* d_in, const int* in_sizes, int n_in,
                              void* d_out, int out_size, void* d_ws, size_t ws_size,
                              hipStream_t stream) {
  const float* x = (const float*)d_in[0];
  const int* ei = (const int*)d_in[1];
  const float* ea = (const float*)d_in[2];
  const float* Wg = (const float*)d_in[3];
  const float* wih = (const float*)d_in[4];
  const float* whh = (const float*)d_in[5];
  const float* bih = (const float*)d_in[6];
  const float* bhh = (const float*)d_in[7];
  const float* W1 = (const float*)d_in[8];
  const float* b1 = (const float*)d_in[9];
  const float* W2 = (const float*)d_in[10];
  const float* b2 = (const float*)d_in[11];
  const float* W3 = (const float*)d_in[12];
  const float* b3 = (const float*)d_in[13];
  const float* W4 = (const float*)d_in[14];
  const float* b4 = (const float*)d_in[15];
  float* out = (float*)d_out;

  // workspace layout (descending alignment: f32/int, then ushort, then uchar)
  float* part = (float*)d_ws;                           // NSLICE*BSZ*64 f32
  int* gcnt = (int*)(part + (size_t)NSLICE * BSZ * 64); // NCB (pad to 384)
  int* off = gcnt + 384;                                // NN
  int* cnt = off + NN;                                  // NN
  int* ent4 = cnt + NN;                                 // NCB*SORTCAP
  int* csr4 = ent4 + (size_t)NCB * SORTCAP;             // NCB*SORTCAP
  ushort* hba = (ushort*)(csr4 + (size_t)NCB * SORTCAP);// NN*64 (ping)
  ushort* hbb = hba + (size_t)NN * 64;                  // NN*64 (pong)
  ushort* m16 = hbb + (size_t)NN * 64;                  // NN*64 (row-major)
  ushort* aggr16 = m16 + (size_t)NN * 64;               // NN*64
  ushort* w1b = aggr16 + (size_t)NN * 64;               // KTOT*HC
  ushort* wihb = w1b + (size_t)KTOT * HC;               // 12288
  ushort* whhb = wihb + 12288;                          // 12288
  ushort* wgnb = whhb + 12288;                          // 4096
  unsigned char* dstlo = (unsigned char*)(wgnb + 4096); // NCB*SORTCAP

  // --- build: partition fused with init (640 + 20480 blocks), then sort ---
  hipMemsetAsync(gcnt, 0, NCB * sizeof(int), stream);
  k_part1<<<NBLK1 + INITB, 256, 0, stream>>>(ei, ea, gcnt, ent4, dstlo,
                                             x, Wg, hba, m16, W1, w1b,
                                             wih, whh, Wg + 64 * 64,
                                             wihb, whhb, wgnb);
  k_sort<<<NCB, 256, 0, stream>>>(ent4, dstlo, gcnt, csr4, off, cnt);

  // layer 0 (gru fuses m = h1 @ Wg[1] for layer 1); h ping-pongs hba->hbb->hba
  k_aggregate<<<2048, 256, 0, stream>>>(off, cnt, csr4, m16, aggr16);
  k_gru_mfma<<<1280, 256, 0, stream>>>(aggr16, hba, hbb, wihb, whhb, bih, bhh,
                                       wgnb, m16);
  // layer 1
  k_aggregate<<<2048, 256, 0, stream>>>(off, cnt, csr4, m16, aggr16);
  k_gru_mfma<<<1280, 256, 0, stream>>>(aggr16, hbb, hba, wihb, whhb, bih, bhh,
                                       nullptr, m16);
  k_mlp1_mfma<<<512, 256, 0, stream>>>(hba, w1b, part);
  k_tail<<<BSZ / 4, 256, 0, stream>>>(part, b1, W2, b2, W3, b3, W4, b4, out);
}